// Round 19
// baseline (38.690 us; speedup 1.0000x reference)
//
#include <hip/hip_runtime.h>
#include <stdint.h>

#define NBOX 8192

// ws layout: float4 sbox[8192] (128 KB) | uint32_t flags[256] (1 KB) |
//            uint32_t cnt[8*32] (panel counters, 128 B apart).
// R19 = R16/R17 pipeline (best, 31.36 us) with ONE change: rank sweep loads
// vectorized to uint4 (4 keys/load; 32 loads/wave instead of 128). R18's
// split-sweep restructure REGRESSED (+7 us) and is reverted.

// ---------------------------------------------------------------------------
// Kernel 1: stable rank by (desc score, asc index), LDS-free, uint4 sweep.
// key = (~score_bits << 32) | index; rank(e) = #{i: key_i < key_e}
//   == jnp.argsort(-score) stable order (scores >= 0 -> bits monotone; keys
//   unique). Wave owns 4 elements; lanes sweep 4 keys/load x 64 lanes.
// Block 0 re-inits flags + panel counters (graph replay safe).
// ---------------------------------------------------------------------------
__global__ __launch_bounds__(256) void nms_rank_kernel(
    const float4* __restrict__ bbox, const uint32_t* __restrict__ sb,
    float4* __restrict__ sbox, uint32_t* __restrict__ flags)
{
    const int tid = threadIdx.x;
    if (blockIdx.x == 0) {
        flags[tid] = 0;                       // 256 words
        if (tid < 8) flags[256 + tid * 32] = 0;   // panel counters
    }

    const int lane = tid & 63;
    const int e0 = (int)blockIdx.x * 16 + (tid >> 6) * 4;  // wave's 4 elements

    uint32_t b0 = sb[e0 + 0], b1 = sb[e0 + 1], b2 = sb[e0 + 2], b3 = sb[e0 + 3];
    const uint64_t k0 = ((uint64_t)(~b0) << 32) | (uint32_t)(e0 + 0);
    const uint64_t k1 = ((uint64_t)(~b1) << 32) | (uint32_t)(e0 + 1);
    const uint64_t k2 = ((uint64_t)(~b2) << 32) | (uint32_t)(e0 + 2);
    const uint64_t k3 = ((uint64_t)(~b3) << 32) | (uint32_t)(e0 + 3);

    const uint4* sb4 = (const uint4*)sb;
    uint32_t c0 = 0, c1 = 0, c2 = 0, c3 = 0;
    #pragma unroll 8
    for (int s = 0; s < 32; ++s) {            // 32 dwordx4 loads = 8192 keys
        uint4 bv = sb4[s * 64 + lane];        // keys i0 .. i0+3, coalesced 16B
        int i0 = s * 256 + lane * 4;
        uint64_t ka = ((uint64_t)(~bv.x) << 32) | (uint32_t)(i0 + 0);
        uint64_t kb = ((uint64_t)(~bv.y) << 32) | (uint32_t)(i0 + 1);
        uint64_t kc = ((uint64_t)(~bv.z) << 32) | (uint32_t)(i0 + 2);
        uint64_t kd = ((uint64_t)(~bv.w) << 32) | (uint32_t)(i0 + 3);
        c0 += (ka < k0) ? 1u : 0u;  c0 += (kb < k0) ? 1u : 0u;
        c0 += (kc < k0) ? 1u : 0u;  c0 += (kd < k0) ? 1u : 0u;
        c1 += (ka < k1) ? 1u : 0u;  c1 += (kb < k1) ? 1u : 0u;
        c1 += (kc < k1) ? 1u : 0u;  c1 += (kd < k1) ? 1u : 0u;
        c2 += (ka < k2) ? 1u : 0u;  c2 += (kb < k2) ? 1u : 0u;
        c2 += (kc < k2) ? 1u : 0u;  c2 += (kd < k2) ? 1u : 0u;
        c3 += (ka < k3) ? 1u : 0u;  c3 += (kb < k3) ? 1u : 0u;
        c3 += (kc < k3) ? 1u : 0u;  c3 += (kd < k3) ? 1u : 0u;
    }
    #pragma unroll
    for (int off = 32; off; off >>= 1) {
        c0 += __shfl_down(c0, off);
        c1 += __shfl_down(c1, off);
        c2 += __shfl_down(c2, off);
        c3 += __shfl_down(c3, off);
    }
    if (lane == 0) {                          // unique ranks, dwordx4 stores
        sbox[c0] = bbox[e0 + 0];
        sbox[c1] = bbox[e0 + 1];
        sbox[c2] = bbox[e0 + 2];
        sbox[c3] = bbox[e0 + 3];
    }
}

// ---------------------------------------------------------------------------
// Kernel 2: T=4 tile suppression + fence-free fused write — R17 verbatim.
// Block = one 32-box i-tile (LDS) x 1024 j-rows (4/thread, stride 256).
// Prefilter fmaf(ih, iw, -0.4110*ia) > 0.4110*ja, conservative (margin
// 7e-4*(ai+aj) >> f32 rounding; union >= 256 so reference 1e-9 clamp is
// identity; x-clamp dropped: non-overlap gives fmaf <= nta < 0 < tk).
// Exact path (rare, ctz walk) replicates reference IEEE f32 op order incl.
// division; __f*_rn blocks fma-contraction.
// ---------------------------------------------------------------------------
__global__ __launch_bounds__(256, 8) void nms_suppress_kernel(
    const float4* __restrict__ sbox, uint32_t* __restrict__ flags,
    float4* __restrict__ out)
{
    __shared__ float4 LB[32];                // i-tile boxes (512 B)
    __shared__ float  LNT[32];               // -0.4110f * area_i
    __shared__ uint32_t FW[32];              // winner: panel flag words
    __shared__ int    winner;

    const int tid = threadIdx.x;
    const int b = (int)blockIdx.x;

    int jb = (int)(sqrtf((float)b * 0.0625f + 0.25f) - 0.5f);
    while (16 * (jb + 1) * (jb + 2) <= b) ++jb;
    while (16 * jb * (jb + 1) > b) --jb;
    const int it = b - 16 * jb * (jb + 1);   // 0 .. 32*jb+31
    const int ibase = it * 32;               // <= 8160
    const int jbase = jb * 1024;

    if (tid < 32) {
        float4 bx = sbox[ibase + tid];
        LB[tid] = bx;
        LNT[tid] = -0.4110f * ((bx.z - bx.x) * (bx.w - bx.y));
    }

    const float4 bj0 = sbox[jbase + tid];
    const float4 bj1 = sbox[jbase + 256 + tid];
    const float4 bj2 = sbox[jbase + 512 + tid];
    const float4 bj3 = sbox[jbase + 768 + tid];
    const float tk0 = 0.4110f * ((bj0.z - bj0.x) * (bj0.w - bj0.y));
    const float tk1 = 0.4110f * ((bj1.z - bj1.x) * (bj1.w - bj1.y));
    const float tk2 = 0.4110f * ((bj2.z - bj2.x) * (bj2.w - bj2.y));
    const float tk3 = 0.4110f * ((bj3.z - bj3.x) * (bj3.w - bj3.y));
    __syncthreads();

    uint32_t c0 = 0, c1 = 0, c2 = 0, c3 = 0;
    #pragma unroll 8
    for (int ii = 31; ii >= 0; --ii) {       // descending: bit k <-> slot k
        const float4 bi = LB[ii];
        const float nta = LNT[ii];
        {
            float ty1 = fmaxf(bi.x, bj0.x), tx1 = fmaxf(bi.y, bj0.y);
            float ty2 = fminf(bi.z, bj0.z), tx2 = fminf(bi.w, bj0.w);
            float ih = fmaxf(ty2 - ty1, 0.0f), iw = tx2 - tx1;
            c0 = c0 + c0 + ((fmaf(ih, iw, nta) > tk0) ? 1u : 0u);
        }
        {
            float ty1 = fmaxf(bi.x, bj1.x), tx1 = fmaxf(bi.y, bj1.y);
            float ty2 = fminf(bi.z, bj1.z), tx2 = fminf(bi.w, bj1.w);
            float ih = fmaxf(ty2 - ty1, 0.0f), iw = tx2 - tx1;
            c1 = c1 + c1 + ((fmaf(ih, iw, nta) > tk1) ? 1u : 0u);
        }
        {
            float ty1 = fmaxf(bi.x, bj2.x), tx1 = fmaxf(bi.y, bj2.y);
            float ty2 = fminf(bi.z, bj2.z), tx2 = fminf(bi.w, bj2.w);
            float ih = fmaxf(ty2 - ty1, 0.0f), iw = tx2 - tx1;
            c2 = c2 + c2 + ((fmaf(ih, iw, nta) > tk2) ? 1u : 0u);
        }
        {
            float ty1 = fmaxf(bi.x, bj3.x), tx1 = fmaxf(bi.y, bj3.y);
            float ty2 = fminf(bi.z, bj3.z), tx2 = fminf(bi.w, bj3.w);
            float ih = fmaxf(ty2 - ty1, 0.0f), iw = tx2 - tx1;
            c3 = c3 + c3 + ((fmaf(ih, iw, nta) > tk3) ? 1u : 0u);
        }
    }

    // diagonal masking: valid slots are ii < j - ibase (full tiles -> ~0u)
    {
        int d0 = jbase + tid - ibase;
        int d1 = d0 + 256, d2 = d0 + 512, d3 = d0 + 768;
        c0 &= (d0 <= 0) ? 0u : ((d0 >= 32) ? ~0u : ((1u << d0) - 1u));
        c1 &= (d1 <= 0) ? 0u : ((d1 >= 32) ? ~0u : ((1u << d1) - 1u));
        c2 &= (d2 <= 0) ? 0u : ((d2 >= 32) ? ~0u : ((1u << d2) - 1u));
        c3 &= (d3 <= 0) ? 0u : ((d3 >= 32) ? ~0u : ((1u << d3) - 1u));
    }

    // rare exact path: reference fp op order, IEEE f32 division
    if (c0 | c1 | c2 | c3) {
        #pragma unroll
        for (int q = 0; q < 4; ++q) {
            uint32_t m = (q == 0) ? c0 : (q == 1) ? c1 : (q == 2) ? c2 : c3;
            if (!m) continue;
            const float4 bj = (q == 0) ? bj0 : (q == 1) ? bj1 : (q == 2) ? bj2 : bj3;
            const float ja = __fmul_rn(__fsub_rn(bj.z, bj.x), __fsub_rn(bj.w, bj.y));
            bool h = false;
            do {
                int k = __builtin_ctz(m); m &= m - 1;
                float4 bi = LB[k];
                float ia = __fmul_rn(__fsub_rn(bi.z, bi.x), __fsub_rn(bi.w, bi.y));
                float ty1 = fmaxf(bi.x, bj.x), tx1 = fmaxf(bi.y, bj.y);
                float ty2 = fminf(bi.z, bj.z), tx2 = fminf(bi.w, bj.w);
                float ih = fmaxf(__fsub_rn(ty2, ty1), 0.0f);
                float iw = fmaxf(__fsub_rn(tx2, tx1), 0.0f);
                float inter = __fmul_rn(ih, iw);
                float un = __fsub_rn(__fadd_rn(ia, ja), inter);
                float iou = inter / fmaxf(un, 1e-9f);
                h |= (iou > 0.7f);
            } while (m);
            if (h) {
                int j = jbase + q * 256 + tid;
                atomicOr(&flags[j >> 5], 1u << (j & 31));
            }
        }
    }

    // ---- fence-free completion: last block of panel writes panel output ----
    __syncthreads();   // drains vmcnt before s_barrier -> ORs at coherent point
    if (tid == 0) {
        uint32_t old = __hip_atomic_fetch_add(flags + 256 + jb * 32, 1u,
                                              __ATOMIC_RELAXED,
                                              __HIP_MEMORY_SCOPE_AGENT);
        winner = (old == (uint32_t)(32 * jb + 31)) ? 1 : 0;
    }
    __syncthreads();

    if (winner) {
        if (tid < 32)                         // coherent-point reads, no L1
            FW[tid] = __hip_atomic_fetch_or(&flags[jb * 32 + tid], 0u,
                                            __ATOMIC_RELAXED,
                                            __HIP_MEMORY_SCOPE_AGENT);
        __syncthreads();
        #pragma unroll
        for (int q = 0; q < 4; ++q) {
            int r = q * 256 + tid;            // row within panel, 0..1023
            bool sup = (FW[r >> 5] >> (r & 31)) & 1u;
            float4 v = sbox[jbase + r];
            if (sup) { v.x = 0.0f; v.y = 0.0f; v.z = 0.0f; v.w = 0.0f; }
            out[jbase + r] = v;
        }
    }
}

extern "C" void kernel_launch(void* const* d_in, const int* in_sizes, int n_in,
                              void* d_out, int out_size, void* d_ws, size_t ws_size,
                              hipStream_t stream) {
    const float4*   bbox  = (const float4*)d_in[0];    // (8192,4) f32
    const uint32_t* sbits = (const uint32_t*)d_in[1];  // (8192,)  f32 bits
    float4* out = (float4*)d_out;                      // (8192,4) f32
    float4* sbox = (float4*)d_ws;                      // 128 KB
    uint32_t* flags = (uint32_t*)((char*)d_ws + NBOX * 16);  // 1 KB + counters

    hipLaunchKernelGGL(nms_rank_kernel, dim3(NBOX / 16), dim3(256), 0, stream,
                       bbox, sbits, sbox, flags);
    // triangular tile grid: sum_{jb=0..7} (32*jb+32) = 1152 blocks of 256 thr
    hipLaunchKernelGGL(nms_suppress_kernel, dim3(1152), dim3(256), 0, stream,
                       sbox, flags, out);
}

// Round 21
// 31.946 us; speedup vs baseline: 1.2111x; 1.2111x over previous
//
#include <hip/hip_runtime.h>
#include <stdint.h>

#define NBOX 8192

// ws layout: float4 sbox[8192] (128 KB) then uint32_t flags[256] (1 KB).
// R21 = SAFE REVERT after R20 tripwire failure. The R15+ fused-write
// (last-block-per-panel relaxed-RMW completion) is a latent race (1 failure
// in 6 runs) — removed. 3-kernel structure, no inter-block communication
// except idempotent flag ORs. Components all individually proven:
//  rank: R13 scalar LDS-free (measured 8.3us, deterministic)
//  suppress: R16 hot loop (fmaf prefilter, c=c+c+cond, unclamped iw), (256,4)
//  write: R13 masked float4 write.

// ---------------------------------------------------------------------------
// Kernel 1: stable rank by (desc score, asc index), LDS-free.
// key = (~score_bits << 32) | index; rank(e) = #{i: key_i < key_e}
//   == jnp.argsort(-score) stable order (scores >= 0 -> bits monotone; keys
//   unique). Wave owns 4 elements; lanes sweep 64 keys/iter from global.
// Block 0 zeroes the flag bitmap (graph replay safe).
// ---------------------------------------------------------------------------
__global__ __launch_bounds__(256) void nms_rank_kernel(
    const float4* __restrict__ bbox, const uint32_t* __restrict__ sb,
    float4* __restrict__ sbox, uint32_t* __restrict__ flags)
{
    const int tid = threadIdx.x;
    if (blockIdx.x == 0) flags[tid] = 0;     // 256 words

    const int lane = tid & 63;
    const int e0 = (int)blockIdx.x * 16 + (tid >> 6) * 4;  // wave's 4 elements

    uint32_t b0 = sb[e0 + 0], b1 = sb[e0 + 1], b2 = sb[e0 + 2], b3 = sb[e0 + 3];
    const uint64_t k0 = ((uint64_t)(~b0) << 32) | (uint32_t)(e0 + 0);
    const uint64_t k1 = ((uint64_t)(~b1) << 32) | (uint32_t)(e0 + 1);
    const uint64_t k2 = ((uint64_t)(~b2) << 32) | (uint32_t)(e0 + 2);
    const uint64_t k3 = ((uint64_t)(~b3) << 32) | (uint32_t)(e0 + 3);

    uint32_t c0 = 0, c1 = 0, c2 = 0, c3 = 0;
    #pragma unroll 8
    for (int s = 0; s < 128; ++s) {
        int i = s * 64 + lane;
        uint32_t b = sb[i];
        uint64_t k = ((uint64_t)(~b) << 32) | (uint32_t)i;
        c0 += (k < k0) ? 1u : 0u;
        c1 += (k < k1) ? 1u : 0u;
        c2 += (k < k2) ? 1u : 0u;
        c3 += (k < k3) ? 1u : 0u;
    }
    #pragma unroll
    for (int off = 32; off; off >>= 1) {
        c0 += __shfl_down(c0, off);
        c1 += __shfl_down(c1, off);
        c2 += __shfl_down(c2, off);
        c3 += __shfl_down(c3, off);
    }
    if (lane == 0) {                          // unique ranks, dwordx4 stores
        sbox[c0] = bbox[e0 + 0];
        sbox[c1] = bbox[e0 + 1];
        sbox[c2] = bbox[e0 + 2];
        sbox[c3] = bbox[e0 + 3];
    }
}

// ---------------------------------------------------------------------------
// Kernel 2: T=4 tile suppression (R16 hot loop, no fused write).
// Block = one 32-box i-tile (LDS) x 1024 j-rows (4/thread, stride 256).
// Prefilter fmaf(ih, iw, -0.4110*ia) > 0.4110*ja, conservative (margin
// 7e-4*(ai+aj) >> f32 rounding; union >= 256 so reference 1e-9 clamp is
// identity; x-clamp dropped: non-overlap gives fmaf <= nta < 0 < tk).
// Exact path (rare, ctz walk) replicates reference IEEE f32 op order incl.
// division; __f*_rn blocks fma-contraction.
// ---------------------------------------------------------------------------
__global__ __launch_bounds__(256, 4) void nms_suppress_kernel(
    const float4* __restrict__ sbox, uint32_t* __restrict__ flags)
{
    __shared__ float4 LB[32];                // i-tile boxes (512 B)
    __shared__ float  LNT[32];               // -0.4110f * area_i

    const int tid = threadIdx.x;
    const int b = (int)blockIdx.x;

    int jb = (int)(sqrtf((float)b * 0.0625f + 0.25f) - 0.5f);
    while (16 * (jb + 1) * (jb + 2) <= b) ++jb;
    while (16 * jb * (jb + 1) > b) --jb;
    const int it = b - 16 * jb * (jb + 1);   // 0 .. 32*jb+31
    const int ibase = it * 32;               // <= 8160
    const int jbase = jb * 1024;

    if (tid < 32) {
        float4 bx = sbox[ibase + tid];
        LB[tid] = bx;
        LNT[tid] = -0.4110f * ((bx.z - bx.x) * (bx.w - bx.y));
    }

    const float4 bj0 = sbox[jbase + tid];
    const float4 bj1 = sbox[jbase + 256 + tid];
    const float4 bj2 = sbox[jbase + 512 + tid];
    const float4 bj3 = sbox[jbase + 768 + tid];
    const float tk0 = 0.4110f * ((bj0.z - bj0.x) * (bj0.w - bj0.y));
    const float tk1 = 0.4110f * ((bj1.z - bj1.x) * (bj1.w - bj1.y));
    const float tk2 = 0.4110f * ((bj2.z - bj2.x) * (bj2.w - bj2.y));
    const float tk3 = 0.4110f * ((bj3.z - bj3.x) * (bj3.w - bj3.y));
    __syncthreads();

    uint32_t c0 = 0, c1 = 0, c2 = 0, c3 = 0;
    #pragma unroll 8
    for (int ii = 31; ii >= 0; --ii) {       // descending: bit k <-> slot k
        const float4 bi = LB[ii];
        const float nta = LNT[ii];
        {
            float ty1 = fmaxf(bi.x, bj0.x), tx1 = fmaxf(bi.y, bj0.y);
            float ty2 = fminf(bi.z, bj0.z), tx2 = fminf(bi.w, bj0.w);
            float ih = fmaxf(ty2 - ty1, 0.0f), iw = tx2 - tx1;
            c0 = c0 + c0 + ((fmaf(ih, iw, nta) > tk0) ? 1u : 0u);
        }
        {
            float ty1 = fmaxf(bi.x, bj1.x), tx1 = fmaxf(bi.y, bj1.y);
            float ty2 = fminf(bi.z, bj1.z), tx2 = fminf(bi.w, bj1.w);
            float ih = fmaxf(ty2 - ty1, 0.0f), iw = tx2 - tx1;
            c1 = c1 + c1 + ((fmaf(ih, iw, nta) > tk1) ? 1u : 0u);
        }
        {
            float ty1 = fmaxf(bi.x, bj2.x), tx1 = fmaxf(bi.y, bj2.y);
            float ty2 = fminf(bi.z, bj2.z), tx2 = fminf(bi.w, bj2.w);
            float ih = fmaxf(ty2 - ty1, 0.0f), iw = tx2 - tx1;
            c2 = c2 + c2 + ((fmaf(ih, iw, nta) > tk2) ? 1u : 0u);
        }
        {
            float ty1 = fmaxf(bi.x, bj3.x), tx1 = fmaxf(bi.y, bj3.y);
            float ty2 = fminf(bi.z, bj3.z), tx2 = fminf(bi.w, bj3.w);
            float ih = fmaxf(ty2 - ty1, 0.0f), iw = tx2 - tx1;
            c3 = c3 + c3 + ((fmaf(ih, iw, nta) > tk3) ? 1u : 0u);
        }
    }

    // diagonal masking: valid slots are ii < j - ibase (full tiles -> ~0u)
    {
        int d0 = jbase + tid - ibase;
        int d1 = d0 + 256, d2 = d0 + 512, d3 = d0 + 768;
        c0 &= (d0 <= 0) ? 0u : ((d0 >= 32) ? ~0u : ((1u << d0) - 1u));
        c1 &= (d1 <= 0) ? 0u : ((d1 >= 32) ? ~0u : ((1u << d1) - 1u));
        c2 &= (d2 <= 0) ? 0u : ((d2 >= 32) ? ~0u : ((1u << d2) - 1u));
        c3 &= (d3 <= 0) ? 0u : ((d3 >= 32) ? ~0u : ((1u << d3) - 1u));
    }

    // rare exact path: reference fp op order, IEEE f32 division
    if (c0 | c1 | c2 | c3) {
        #pragma unroll
        for (int q = 0; q < 4; ++q) {
            uint32_t m = (q == 0) ? c0 : (q == 1) ? c1 : (q == 2) ? c2 : c3;
            if (!m) continue;
            const float4 bj = (q == 0) ? bj0 : (q == 1) ? bj1 : (q == 2) ? bj2 : bj3;
            const float ja = __fmul_rn(__fsub_rn(bj.z, bj.x), __fsub_rn(bj.w, bj.y));
            bool h = false;
            do {
                int k = __builtin_ctz(m); m &= m - 1;
                float4 bi = LB[k];
                float ia = __fmul_rn(__fsub_rn(bi.z, bi.x), __fsub_rn(bi.w, bi.y));
                float ty1 = fmaxf(bi.x, bj.x), tx1 = fmaxf(bi.y, bj.y);
                float ty2 = fminf(bi.z, bj.z), tx2 = fminf(bi.w, bj.w);
                float ih = fmaxf(__fsub_rn(ty2, ty1), 0.0f);
                float iw = fmaxf(__fsub_rn(tx2, tx1), 0.0f);
                float inter = __fmul_rn(ih, iw);
                float un = __fsub_rn(__fadd_rn(ia, ja), inter);
                float iou = inter / fmaxf(un, 1e-9f);
                h |= (iou > 0.7f);
            } while (m);
            if (h) {
                int j = jbase + q * 256 + tid;
                atomicOr(&flags[j >> 5], 1u << (j & 31));
            }
        }
    }
}

// ---------------------------------------------------------------------------
// Kernel 3: masked float4 write of sorted boxes.
// ---------------------------------------------------------------------------
__global__ __launch_bounds__(256) void nms_write_kernel(
    const float4* __restrict__ sbox, const uint32_t* __restrict__ flags,
    float4* __restrict__ out)
{
    int j = blockIdx.x * 256 + threadIdx.x;
    bool sup = (flags[j >> 5] >> (j & 31)) & 1u;
    float4 v = sbox[j];
    if (sup) { v.x = 0.0f; v.y = 0.0f; v.z = 0.0f; v.w = 0.0f; }
    out[j] = v;
}

extern "C" void kernel_launch(void* const* d_in, const int* in_sizes, int n_in,
                              void* d_out, int out_size, void* d_ws, size_t ws_size,
                              hipStream_t stream) {
    const float4*   bbox  = (const float4*)d_in[0];    // (8192,4) f32
    const uint32_t* sbits = (const uint32_t*)d_in[1];  // (8192,)  f32 bits
    float4* out = (float4*)d_out;                      // (8192,4) f32
    float4* sbox = (float4*)d_ws;                      // 128 KB
    uint32_t* flags = (uint32_t*)((char*)d_ws + NBOX * 16);  // 1 KB

    hipLaunchKernelGGL(nms_rank_kernel, dim3(NBOX / 16), dim3(256), 0, stream,
                       bbox, sbits, sbox, flags);
    // triangular tile grid: sum_{jb=0..7} (32*jb+32) = 1152 blocks of 256 thr
    hipLaunchKernelGGL(nms_suppress_kernel, dim3(1152), dim3(256), 0, stream,
                       sbox, flags);
    hipLaunchKernelGGL(nms_write_kernel, dim3(NBOX / 256), dim3(256), 0, stream,
                       sbox, flags, out);
}

// Round 22
// 31.103 us; speedup vs baseline: 1.2439x; 1.0271x over previous
//
#include <hip/hip_runtime.h>
#include <stdint.h>

#define NBOX 8192

// ws layout: float4 sbox[8192] (128 KB) then uint32_t flags[256] (1 KB).
// R22 = R21 (race-free 3-kernel baseline, 31.95us) with ONE change:
// rank sweep vectorized to uint4 (32 dwordx4 loads/wave instead of 128
// scalar; same VALU count/key -> latency-bound 8.3us -> ~4.8us predicted).
// Clean single-variable test (R19 confounded it with suppress(256,8);
// R20 confounded it with the now-removed completion race).

// ---------------------------------------------------------------------------
// Kernel 1: stable rank by (desc score, asc index), LDS-free, uint4 sweep.
// key = (~score_bits << 32) | index; rank(e) = #{i: key_i < key_e}
//   == jnp.argsort(-score) stable order (scores >= 0 -> bits monotone; keys
//   unique). Wave owns 4 elements; 32 dwordx4 loads (4 keys each), coalesced.
// Block 0 zeroes the flag bitmap (graph replay safe).
// ---------------------------------------------------------------------------
__global__ __launch_bounds__(256) void nms_rank_kernel(
    const float4* __restrict__ bbox, const uint32_t* __restrict__ sb,
    float4* __restrict__ sbox, uint32_t* __restrict__ flags)
{
    const int tid = threadIdx.x;
    if (blockIdx.x == 0) flags[tid] = 0;     // 256 words

    const int lane = tid & 63;
    const int e0 = (int)blockIdx.x * 16 + (tid >> 6) * 4;  // wave's 4 elements

    uint32_t b0 = sb[e0 + 0], b1 = sb[e0 + 1], b2 = sb[e0 + 2], b3 = sb[e0 + 3];
    const uint64_t k0 = ((uint64_t)(~b0) << 32) | (uint32_t)(e0 + 0);
    const uint64_t k1 = ((uint64_t)(~b1) << 32) | (uint32_t)(e0 + 1);
    const uint64_t k2 = ((uint64_t)(~b2) << 32) | (uint32_t)(e0 + 2);
    const uint64_t k3 = ((uint64_t)(~b3) << 32) | (uint32_t)(e0 + 3);

    const uint4* sb4 = (const uint4*)sb;
    uint32_t c0 = 0, c1 = 0, c2 = 0, c3 = 0;
    #pragma unroll 8
    for (int s = 0; s < 32; ++s) {            // 32 dwordx4 loads = 8192 keys
        uint4 bv = sb4[s * 64 + lane];        // keys i0 .. i0+3, coalesced 16B
        int i0 = s * 256 + lane * 4;
        uint64_t ka = ((uint64_t)(~bv.x) << 32) | (uint32_t)(i0 + 0);
        uint64_t kb = ((uint64_t)(~bv.y) << 32) | (uint32_t)(i0 + 1);
        uint64_t kc = ((uint64_t)(~bv.z) << 32) | (uint32_t)(i0 + 2);
        uint64_t kd = ((uint64_t)(~bv.w) << 32) | (uint32_t)(i0 + 3);
        c0 += (ka < k0) ? 1u : 0u;  c0 += (kb < k0) ? 1u : 0u;
        c0 += (kc < k0) ? 1u : 0u;  c0 += (kd < k0) ? 1u : 0u;
        c1 += (ka < k1) ? 1u : 0u;  c1 += (kb < k1) ? 1u : 0u;
        c1 += (kc < k1) ? 1u : 0u;  c1 += (kd < k1) ? 1u : 0u;
        c2 += (ka < k2) ? 1u : 0u;  c2 += (kb < k2) ? 1u : 0u;
        c2 += (kc < k2) ? 1u : 0u;  c2 += (kd < k2) ? 1u : 0u;
        c3 += (ka < k3) ? 1u : 0u;  c3 += (kb < k3) ? 1u : 0u;
        c3 += (kc < k3) ? 1u : 0u;  c3 += (kd < k3) ? 1u : 0u;
    }
    #pragma unroll
    for (int off = 32; off; off >>= 1) {
        c0 += __shfl_down(c0, off);
        c1 += __shfl_down(c1, off);
        c2 += __shfl_down(c2, off);
        c3 += __shfl_down(c3, off);
    }
    if (lane == 0) {                          // unique ranks, dwordx4 stores
        sbox[c0] = bbox[e0 + 0];
        sbox[c1] = bbox[e0 + 1];
        sbox[c2] = bbox[e0 + 2];
        sbox[c3] = bbox[e0 + 3];
    }
}

// ---------------------------------------------------------------------------
// Kernel 2: T=4 tile suppression — R21 verbatim ((256,4), no fused write).
// Block = one 32-box i-tile (LDS) x 1024 j-rows (4/thread, stride 256).
// Prefilter fmaf(ih, iw, -0.4110*ia) > 0.4110*ja, conservative (margin
// 7e-4*(ai+aj) >> f32 rounding; union >= 256 so reference 1e-9 clamp is
// identity; x-clamp dropped: non-overlap gives fmaf <= nta < 0 < tk).
// Exact path (rare, ctz walk) replicates reference IEEE f32 op order incl.
// division; __f*_rn blocks fma-contraction.
// ---------------------------------------------------------------------------
__global__ __launch_bounds__(256, 4) void nms_suppress_kernel(
    const float4* __restrict__ sbox, uint32_t* __restrict__ flags)
{
    __shared__ float4 LB[32];                // i-tile boxes (512 B)
    __shared__ float  LNT[32];               // -0.4110f * area_i

    const int tid = threadIdx.x;
    const int b = (int)blockIdx.x;

    int jb = (int)(sqrtf((float)b * 0.0625f + 0.25f) - 0.5f);
    while (16 * (jb + 1) * (jb + 2) <= b) ++jb;
    while (16 * jb * (jb + 1) > b) --jb;
    const int it = b - 16 * jb * (jb + 1);   // 0 .. 32*jb+31
    const int ibase = it * 32;               // <= 8160
    const int jbase = jb * 1024;

    if (tid < 32) {
        float4 bx = sbox[ibase + tid];
        LB[tid] = bx;
        LNT[tid] = -0.4110f * ((bx.z - bx.x) * (bx.w - bx.y));
    }

    const float4 bj0 = sbox[jbase + tid];
    const float4 bj1 = sbox[jbase + 256 + tid];
    const float4 bj2 = sbox[jbase + 512 + tid];
    const float4 bj3 = sbox[jbase + 768 + tid];
    const float tk0 = 0.4110f * ((bj0.z - bj0.x) * (bj0.w - bj0.y));
    const float tk1 = 0.4110f * ((bj1.z - bj1.x) * (bj1.w - bj1.y));
    const float tk2 = 0.4110f * ((bj2.z - bj2.x) * (bj2.w - bj2.y));
    const float tk3 = 0.4110f * ((bj3.z - bj3.x) * (bj3.w - bj3.y));
    __syncthreads();

    uint32_t c0 = 0, c1 = 0, c2 = 0, c3 = 0;
    #pragma unroll 8
    for (int ii = 31; ii >= 0; --ii) {       // descending: bit k <-> slot k
        const float4 bi = LB[ii];
        const float nta = LNT[ii];
        {
            float ty1 = fmaxf(bi.x, bj0.x), tx1 = fmaxf(bi.y, bj0.y);
            float ty2 = fminf(bi.z, bj0.z), tx2 = fminf(bi.w, bj0.w);
            float ih = fmaxf(ty2 - ty1, 0.0f), iw = tx2 - tx1;
            c0 = c0 + c0 + ((fmaf(ih, iw, nta) > tk0) ? 1u : 0u);
        }
        {
            float ty1 = fmaxf(bi.x, bj1.x), tx1 = fmaxf(bi.y, bj1.y);
            float ty2 = fminf(bi.z, bj1.z), tx2 = fminf(bi.w, bj1.w);
            float ih = fmaxf(ty2 - ty1, 0.0f), iw = tx2 - tx1;
            c1 = c1 + c1 + ((fmaf(ih, iw, nta) > tk1) ? 1u : 0u);
        }
        {
            float ty1 = fmaxf(bi.x, bj2.x), tx1 = fmaxf(bi.y, bj2.y);
            float ty2 = fminf(bi.z, bj2.z), tx2 = fminf(bi.w, bj2.w);
            float ih = fmaxf(ty2 - ty1, 0.0f), iw = tx2 - tx1;
            c2 = c2 + c2 + ((fmaf(ih, iw, nta) > tk2) ? 1u : 0u);
        }
        {
            float ty1 = fmaxf(bi.x, bj3.x), tx1 = fmaxf(bi.y, bj3.y);
            float ty2 = fminf(bi.z, bj3.z), tx2 = fminf(bi.w, bj3.w);
            float ih = fmaxf(ty2 - ty1, 0.0f), iw = tx2 - tx1;
            c3 = c3 + c3 + ((fmaf(ih, iw, nta) > tk3) ? 1u : 0u);
        }
    }

    // diagonal masking: valid slots are ii < j - ibase (full tiles -> ~0u)
    {
        int d0 = jbase + tid - ibase;
        int d1 = d0 + 256, d2 = d0 + 512, d3 = d0 + 768;
        c0 &= (d0 <= 0) ? 0u : ((d0 >= 32) ? ~0u : ((1u << d0) - 1u));
        c1 &= (d1 <= 0) ? 0u : ((d1 >= 32) ? ~0u : ((1u << d1) - 1u));
        c2 &= (d2 <= 0) ? 0u : ((d2 >= 32) ? ~0u : ((1u << d2) - 1u));
        c3 &= (d3 <= 0) ? 0u : ((d3 >= 32) ? ~0u : ((1u << d3) - 1u));
    }

    // rare exact path: reference fp op order, IEEE f32 division
    if (c0 | c1 | c2 | c3) {
        #pragma unroll
        for (int q = 0; q < 4; ++q) {
            uint32_t m = (q == 0) ? c0 : (q == 1) ? c1 : (q == 2) ? c2 : c3;
            if (!m) continue;
            const float4 bj = (q == 0) ? bj0 : (q == 1) ? bj1 : (q == 2) ? bj2 : bj3;
            const float ja = __fmul_rn(__fsub_rn(bj.z, bj.x), __fsub_rn(bj.w, bj.y));
            bool h = false;
            do {
                int k = __builtin_ctz(m); m &= m - 1;
                float4 bi = LB[k];
                float ia = __fmul_rn(__fsub_rn(bi.z, bi.x), __fsub_rn(bi.w, bi.y));
                float ty1 = fmaxf(bi.x, bj.x), tx1 = fmaxf(bi.y, bj.y);
                float ty2 = fminf(bi.z, bj.z), tx2 = fminf(bi.w, bj.w);
                float ih = fmaxf(__fsub_rn(ty2, ty1), 0.0f);
                float iw = fmaxf(__fsub_rn(tx2, tx1), 0.0f);
                float inter = __fmul_rn(ih, iw);
                float un = __fsub_rn(__fadd_rn(ia, ja), inter);
                float iou = inter / fmaxf(un, 1e-9f);
                h |= (iou > 0.7f);
            } while (m);
            if (h) {
                int j = jbase + q * 256 + tid;
                atomicOr(&flags[j >> 5], 1u << (j & 31));
            }
        }
    }
}

// ---------------------------------------------------------------------------
// Kernel 3: masked float4 write of sorted boxes.
// ---------------------------------------------------------------------------
__global__ __launch_bounds__(256) void nms_write_kernel(
    const float4* __restrict__ sbox, const uint32_t* __restrict__ flags,
    float4* __restrict__ out)
{
    int j = blockIdx.x * 256 + threadIdx.x;
    bool sup = (flags[j >> 5] >> (j & 31)) & 1u;
    float4 v = sbox[j];
    if (sup) { v.x = 0.0f; v.y = 0.0f; v.z = 0.0f; v.w = 0.0f; }
    out[j] = v;
}

extern "C" void kernel_launch(void* const* d_in, const int* in_sizes, int n_in,
                              void* d_out, int out_size, void* d_ws, size_t ws_size,
                              hipStream_t stream) {
    const float4*   bbox  = (const float4*)d_in[0];    // (8192,4) f32
    const uint32_t* sbits = (const uint32_t*)d_in[1];  // (8192,)  f32 bits
    float4* out = (float4*)d_out;                      // (8192,4) f32
    float4* sbox = (float4*)d_ws;                      // 128 KB
    uint32_t* flags = (uint32_t*)((char*)d_ws + NBOX * 16);  // 1 KB

    hipLaunchKernelGGL(nms_rank_kernel, dim3(NBOX / 16), dim3(256), 0, stream,
                       bbox, sbits, sbox, flags);
    // triangular tile grid: sum_{jb=0..7} (32*jb+32) = 1152 blocks of 256 thr
    hipLaunchKernelGGL(nms_suppress_kernel, dim3(1152), dim3(256), 0, stream,
                       sbox, flags);
    hipLaunchKernelGGL(nms_write_kernel, dim3(NBOX / 256), dim3(256), 0, stream,
                       sbox, flags, out);
}